// Round 8
// baseline (292.570 us; speedup 1.0000x reference)
//
#include <hip/hip_runtime.h>
#include <math.h>

#define B_   16
#define V_   16
#define C_   64
#define M_   32
#define CM_  16
#define D_   128
#define OUT_ 600
#define NSEQ 256      // B*V
#define NROW 8192     // B*V*M

typedef __attribute__((ext_vector_type(8))) short bf16x8;
typedef __attribute__((ext_vector_type(4))) short bf16x4;
typedef __attribute__((ext_vector_type(4))) float f32x4;
typedef __attribute__((ext_vector_type(4))) unsigned int u32x4;

__device__ __forceinline__ unsigned short f2bf(float x) {
  union { float f; unsigned u; } v; v.f = x;
  unsigned r = v.u + 0x7fff + ((v.u >> 16) & 1);   // RNE
  return (unsigned short)(r >> 16);
}
__device__ __forceinline__ float bf2f(short s) {
  union { unsigned u; float f; } v;
  v.u = ((unsigned)(unsigned short)s) << 16;
  return v.f;
}
// fast sigmoid / tanh: native v_exp + v_rcp (~5 inst), saturate correctly
__device__ __forceinline__ float fsig(float x)  { return __fdividef(1.f, 1.f + __expf(-x)); }
__device__ __forceinline__ float ftanh(float x) { return 1.f - 2.f*__fdividef(1.f, __expf(2.f*x) + 1.f); }

// LDS-only barrier: drains LDS ops for cross-wave visibility but does NOT
// drain vmcnt — in-flight global prefetch loads survive the barrier.
__device__ __forceinline__ void ldsbar() {
  asm volatile("s_waitcnt lgkmcnt(0)" ::: "memory");
  __builtin_amdgcn_s_barrier();
  asm volatile("" ::: "memory");
}

// manual 16B global load — keeps waitcnt control out of the compiler.
#define GLD4(dst, ptr, offstr) \
  asm volatile("global_load_dwordx4 %0, %1, off offset:" offstr \
               : "=v"(dst) : "v"(ptr) : "memory")

// ---- workspace layout (float units; bf16 arrays are short* views) ----
constexpr int OFF_VIS   = 0;                               // fp32 [3][256][128]
constexpr int OFF_VISB  = 98304;                           // bf16 [3][256][128]
constexpr int OFF_MONB  = 147456;                          // bf16 [2][8192][128]
constexpr int OFF_TOTB  = 1196032;                         // bf16 [2][8192][128]
constexpr int OFF_W12T  = 2244608;                         // bf16 [8][128n][256k]
constexpr int OFF_WIHB  = 2375680;                         // bf16 [5][384n][128k]
constexpr int OFF_WIHTV = 2498560;                         // fp32 [4][128][384]
constexpr int OFF_XE    = 2695168;                         // fp32 [2][256][128]
constexpr int OFF_LAST  = 27926528;                        // fp32 [8][256][128]
constexpr int OFF_VH    = 29171712;                        // fp32 [10][16][128]

// =====================================================================
// prep+vis merged — verified, unchanged.
// =====================================================================
__global__ __launch_bounds__(256) void k_prepvis(
    const float* __restrict__ Wself, const float* __restrict__ Wmsg,
    const float* __restrict__ mWih,  const float* __restrict__ vWih,
    const float* __restrict__ wgt,   const float* __restrict__ age,
    const float* __restrict__ fwW,   const float* __restrict__ fwB,
    const float* __restrict__ faW,   const float* __restrict__ faB,
    const int* __restrict__ cc, const int* __restrict__ cp, const int* __restrict__ cd,
    const float* __restrict__ ec, const float* __restrict__ ep, const float* __restrict__ ed,
    short* __restrict__ w12t, short* __restrict__ wihb,
    float* __restrict__ wihTv, float* __restrict__ xe,
    float* __restrict__ vis, short* __restrict__ visb)
{
  int bx = blockIdx.x, tid = threadIdx.x;
  if (bx < 1024) {                      // w12t[pt][n][k] = bf16 combined
    int lin = bx*256 + tid;             // < 262144
    int pt = lin >> 15, rem = lin & 32767;
    int n = rem >> 8, k = rem & 255;
    float v;
    if (k < 128) v = Wself[pt*16384 + k*128 + n] - Wmsg[pt*16384 + k*128 + n]*(1.f/3.f);
    else         v = Wmsg[pt*16384 + (k-128)*128 + n]*(1.f/3.f);
    w12t[lin] = (short)f2bf(v);
  } else if (bx < 1984) {               // wihb = bf16(mWih) elementwise
    int lin = (bx-1024)*256 + tid;      // < 245760
    wihb[lin] = (short)f2bf(mWih[lin]);
  } else if (bx < 2752) {               // vgru Wih transpose fp32
    int lin = (bx-1984)*256 + tid;      // < 196608
    int g = lin / 49152, rem2 = lin % 49152;
    int k = rem2 / 384, j = rem2 % 384;
    wihTv[lin] = vWih[g*49152 + j*128 + k];
  } else if (bx < 3008) {               // xe for weight / age
    int lin = (bx-2752)*256 + tid;      // < 65536
    int which = lin >> 15, rem2 = lin & 32767;
    int n = rem2 >> 7, d = rem2 & 127;
    float x  = which ? age[n] : wgt[n];
    float Wv = which ? faW[d] : fwW[d];
    float bb = which ? faB[d] : fwB[d];
    xe[lin] = (x != 0.0f) ? (x*Wv + bb) : 0.0f;
  } else {                              // visit-event sum pools
    int idx = (bx-3008)*256 + tid;      // < 98304
    int type = idx >> 15;
    int r = idx & 32767;
    int bv = r >> 7, d = r & 127;
    const int*   codes = (type==0) ? cc : (type==1) ? cp : cd;
    const float* emb   = (type==0) ? ec : (type==1) ? ep : ed;
    float acc = 0.f;
    for (int c = 0; c < C_; ++c) {
      int code = codes[bv*C_ + c];
      acc += emb[code*D_ + d];
    }
    vis [(type*NSEQ + bv)*D_ + d] = acc;
    visb[(type*NSEQ + bv)*D_ + d] = (short)f2bf(acc);
  }
}

// =====================================================================
// monitor-event pools — unchanged (verified).
// =====================================================================
__global__ __launch_bounds__(128) void k_mon(
    const int* __restrict__ cli, const int* __restrict__ clv,
    const int* __restrict__ cii, const int* __restrict__ civ,
    const float* __restrict__ eli, const float* __restrict__ elv,
    const float* __restrict__ eii, const float* __restrict__ eiv,
    const float* __restrict__ vis,
    short* __restrict__ monb, short* __restrict__ totb)
{
  int p   = blockIdx.x >> 13;
  int bvm = blockIdx.x & 8191;
  int d   = threadIdx.x;
  const int* ci = p ? cii : cli;  const int* cv = p ? civ : clv;
  const float* ei = p ? eii : eli; const float* ev = p ? eiv : elv;
  float acc = 0.f;
  #pragma unroll
  for (int c = 0; c < CM_; ++c) {
    int iv = ci[bvm*CM_ + c];
    int vv = cv[bvm*CM_ + c];
    acc += ei[iv*D_ + d] * ev[vv*D_ + d];
  }
  int bv = bvm >> 5;
  float vsum = vis[bv*D_ + d] + vis[(NSEQ + bv)*D_ + d] + vis[(2*NSEQ + bv)*D_ + d];
  monb[(p*NROW + bvm)*D_ + d] = (short)f2bf(acc);
  totb[(p*NROW + bvm)*D_ + d] = (short)f2bf(acc + vsum);
}

// =====================================================================
// FUSED GNN+GI+monitor-GRU (k_ggru v3) — THIS ROUND: PHASE-SPLIT.
// Phase 1 (barrier-free, throughput-bound): all 32 Y(m) tiles.
//   Each wave builds A-frags DIRECTLY from global (lane-scattered rows,
//   L2-resident, counted vmcnt(8) double-buffer) — no LDS staging, no
//   barriers. Y -> 128 KB XOR-swizzled LDS slab (fits with hb: 141 KB).
// Phase 2 (latency-bound, minimal): the proven k_mgru-shaped step —
//   8 LDS reads + 24 MFMA (8-deep chains SPLIT into parallel 4+4) +
//   lane-local activation + ONE ldsbar. No global loads at all.
// =====================================================================
__global__ __launch_bounds__(512, 1) void k_ggru(
    const short* __restrict__ monb, const short* __restrict__ totb,
    const short* __restrict__ visb, const short* __restrict__ w12t,
    const short* __restrict__ wihb, const float* __restrict__ mWhh,
    const float* __restrict__ mbih, const float* __restrict__ mbhh,
    float* __restrict__ last)
{
  const int run  = blockIdx.x >> 4;     // 0..7
  const int pair = blockIdx.x & 15;     // batch b
  const int p = run >> 2, t = run & 3;
  const int g = (run % 4 == 0) ? (run / 4) : (run % 4 + 1);
  const int tid = threadIdx.x;
  const int w = tid >> 6;               // wave 0..7 = hidden slice
  const int lane = tid & 63;
  const int c = lane & 15, q = lane >> 4;
  const int j = w*16 + c;               // hidden index 0..127

  __shared__ short YsAll[32*2048];              // 131072 B, XOR-swizzled
  __shared__ short hb[2][4][16][40];            // 10240 B (v8-verified layout)

  for (int idx = tid; idx < 2*4*16*40; idx += 512)
    ((short*)hb)[idx] = 0;

  // ---- stage1 B-frags: w12t[run][n=w*16+c][k], K=256 -> 8 frags ----
  bf16x8 bW12[8];
  #pragma unroll
  for (int kt = 0; kt < 8; ++kt)
    bW12[kt] = *(const bf16x8*)(w12t + (size_t)run*32768 + (size_t)j*256 + kt*32 + q*8);

  // ---- phase 1: Y(m) for all m, barrier-free ----
  // A-frag rows straight from global: lane (c=seq,q) reads feat/tot row
  // bvm = (pair*16+c)*32 + m at col kt*32+q*8 (16B each).
  const short* fA = (t == 0)
      ? monb + ((size_t)p*NROW + (size_t)(pair*16 + c)*32)*128 + q*8
      : visb + ((size_t)(t-1)*NSEQ + pair*16 + c)*128 + q*8;
  const int fAstride = (t == 0) ? 128 : 0;   // shorts per m
  const short* tA = totb + ((size_t)p*NROW + (size_t)(pair*16 + c)*32)*128 + q*8;

  const short* fp = fA;
  const short* tp = tA;
  u32x4 pfA[8], pfB[8];

  auto issue8 = [&](u32x4 (&buf)[8]) {
    GLD4(buf[0], fp, "0");   GLD4(buf[1], fp, "64");
    GLD4(buf[2], fp, "128"); GLD4(buf[3], fp, "192");
    GLD4(buf[4], tp, "0");   GLD4(buf[5], tp, "64");
    GLD4(buf[6], tp, "128"); GLD4(buf[7], tp, "192");
    fp += fAstride; tp += 128;
  };
  auto computeY = [&](u32x4 (&buf)[8], int m) {
    f32x4 ya = (f32x4){0.f,0.f,0.f,0.f};
    f32x4 yb = (f32x4){0.f,0.f,0.f,0.f};
    #pragma unroll
    for (int kt = 0; kt < 4; ++kt) {
      ya = __builtin_amdgcn_mfma_f32_16x16x32_bf16(*(bf16x8*)&buf[kt],   bW12[kt],   ya, 0, 0, 0);
      yb = __builtin_amdgcn_mfma_f32_16x16x32_bf16(*(bf16x8*)&buf[kt+4], bW12[kt+4], yb, 0, 0, 0);
    }
    char* ybase = (char*)YsAll + m*4096;
    #pragma unroll
    for (int reg = 0; reg < 4; ++reg) {
      int srow = q*4 + reg;
      *(short*)(ybase + srow*256 + ((2*j) ^ ((srow&7)<<4)))
          = (short)f2bf(fmaxf(ya[reg] + yb[reg], 0.f));
    }
  };

  issue8(pfA);                                 // m=0
  #pragma unroll 1
  for (int m2 = 0; m2 < 15; ++m2) {
    issue8(pfB);                               // m = 2*m2+1
    asm volatile("s_waitcnt vmcnt(8)" ::: "memory");
    __builtin_amdgcn_sched_barrier(0);
    computeY(pfA, 2*m2);
    issue8(pfA);                               // m = 2*m2+2
    asm volatile("s_waitcnt vmcnt(8)" ::: "memory");
    __builtin_amdgcn_sched_barrier(0);
    computeY(pfB, 2*m2 + 1);
  }
  issue8(pfB);                                 // m=31
  asm volatile("s_waitcnt vmcnt(8)" ::: "memory");
  __builtin_amdgcn_sched_barrier(0);
  computeY(pfA, 30);
  asm volatile("s_waitcnt vmcnt(0)" ::: "memory");
  __builtin_amdgcn_sched_barrier(0);
  computeY(pfB, 31);

  // ---- phase-2 weights (loaded after phase 1 to cap VGPR peak) ----
  bf16x8 bWih[3][4];
  #pragma unroll
  for (int gate = 0; gate < 3; ++gate)
    #pragma unroll
    for (int kt = 0; kt < 4; ++kt)
      bWih[gate][kt] = *(const bf16x8*)(wihb + ((size_t)g*384 + gate*128 + j)*128 + kt*32 + q*8);

  bf16x8 bWhh[3][4];
  #pragma unroll
  for (int gate = 0; gate < 3; ++gate) {
    const float* wp = mWhh + ((size_t)g*384 + gate*128 + j)*128 + q*8;
    #pragma unroll
    for (int kt = 0; kt < 4; ++kt) {
      float4 lo = *(const float4*)(wp + kt*32);
      float4 hi = *(const float4*)(wp + kt*32 + 4);
      bf16x8 tt;
      tt[0]=(short)f2bf(lo.x); tt[1]=(short)f2bf(lo.y); tt[2]=(short)f2bf(lo.z); tt[3]=(short)f2bf(lo.w);
      tt[4]=(short)f2bf(hi.x); tt[5]=(short)f2bf(hi.y); tt[6]=(short)f2bf(hi.z); tt[7]=(short)f2bf(hi.w);
      bWhh[gate][kt] = tt;
    }
  }
  const float bs0 = mbih[g*384 +       j] + mbhh[g*384 +       j];
  const float bs1 = mbih[g*384 + 128 + j] + mbhh[g*384 + 128 + j];
  const float bi2 = mbih[g*384 + 256 + j];
  const float bh2 = mbhh[g*384 + 256 + j];

  float hf[4] = {0.f,0.f,0.f,0.f};
  const int ktw = w >> 1;               // j>>5
  const int kkw = (w & 1)*16 + c;       // j&31

  ldsbar();   // YsAll (all waves) + hb zero-init visible

  // ---- phase 2: the 32-step recurrence, minimal step ----
  #pragma unroll 1
  for (int m = 0; m < 32; ++m) {
    const int cur = m & 1, nxt = cur ^ 1;
    bf16x8 ah[4], a2[4];
    const char* yb2 = (const char*)YsAll + m*4096;
    #pragma unroll
    for (int kt = 0; kt < 4; ++kt) {
      ah[kt] = *(const bf16x8*)&hb[cur][kt][c][q*8];
      a2[kt] = *(const bf16x8*)(yb2 + c*256 + ((kt*64 + q*16) ^ ((c&7)<<4)));
    }
    // split 8-deep chains into parallel 4+4 (halves dependent depth)
    f32x4 a0a = (f32x4){0.f,0.f,0.f,0.f}, a0b = (f32x4){0.f,0.f,0.f,0.f};
    f32x4 a1a = (f32x4){0.f,0.f,0.f,0.f}, a1b = (f32x4){0.f,0.f,0.f,0.f};
    f32x4 aG2 = (f32x4){0.f,0.f,0.f,0.f}, aH2 = (f32x4){0.f,0.f,0.f,0.f};
    #pragma unroll
    for (int kt = 0; kt < 4; ++kt) {
      a0a = __builtin_amdgcn_mfma_f32_16x16x32_bf16(ah[kt], bWhh[0][kt], a0a, 0, 0, 0);
      a0b = __builtin_amdgcn_mfma_f32_16x16x32_bf16(a2[kt], bWih[0][kt], a0b, 0, 0, 0);
      a1a = __builtin_amdgcn_mfma_f32_16x16x32_bf16(ah[kt], bWhh[1][kt], a1a, 0, 0, 0);
      a1b = __builtin_amdgcn_mfma_f32_16x16x32_bf16(a2[kt], bWih[1][kt], a1b, 0, 0, 0);
      aH2 = __builtin_amdgcn_mfma_f32_16x16x32_bf16(ah[kt], bWhh[2][kt], aH2, 0, 0, 0);
      aG2 = __builtin_amdgcn_mfma_f32_16x16x32_bf16(a2[kt], bWih[2][kt], aG2, 0, 0, 0);
    }
    #pragma unroll
    for (int reg = 0; reg < 4; ++reg) {
      float rr = fsig(a0a[reg] + a0b[reg] + bs0);
      float zz = fsig(a1a[reg] + a1b[reg] + bs1);
      float nn = ftanh(aG2[reg] + bi2 + rr*(aH2[reg] + bh2));
      float hnew = (1.f - zz)*nn + zz*hf[reg];
      hf[reg] = hnew;
      hb[nxt][ktw][q*4 + reg][kkw] = (short)f2bf(hnew);
    }
    ldsbar();   // hb(nxt) visible for step m+1
  }

  #pragma unroll
  for (int reg = 0; reg < 4; ++reg)
    last[((size_t)run*NSEQ + pair*16 + q*4 + reg)*D_ + j] = hf[reg];
}

// =====================================================================
// visit-level GRU v3 (vgi fused) — verified, unchanged.
// =====================================================================
__global__ __launch_bounds__(768) void k_vgru(
    const float* __restrict__ last, const float* __restrict__ xe,
    const float* __restrict__ wihTv, const float* __restrict__ vbih,
    const float* __restrict__ vWhh, const float* __restrict__ vbhh,
    float* __restrict__ vh)
{
  int run = blockIdx.x >> 4, b = blockIdx.x & 15;
  int tid = threadIdx.x;
  int vidx = (run < 4) ? 0 : (run < 8) ? 1 : (run - 6);

  __shared__ float Xs[16][128];          // 8 KB
  __shared__ float giL[16*384];          // 24 KB
  __shared__ __align__(16) float hsv[128];
  __shared__ float gh[384];

  const float* X = (run < 8) ? (last + ((size_t)run*NSEQ + b*16)*D_)
                             : (xe + ((size_t)(run-8)*NSEQ + b*16)*D_);
  for (int idx = tid; idx < 2048; idx += 768)
    ((float*)Xs)[idx] = X[idx];
  if (tid < 128) hsv[tid] = 0.f;
  __syncthreads();

  // ---- gi precompute into LDS: thread (half, j) does 8 visits ----
  {
    int half = (tid >= 384) ? 1 : 0;
    int j = tid - half*384;
    float accv[8];
    float bias = vbih[vidx*384 + j];
    #pragma unroll
    for (int s = 0; s < 8; ++s) accv[s] = bias;
    const float* W = wihTv + vidx*49152 + j;
    #pragma unroll 4
    for (int k = 0; k < 128; ++k) {
      float wv = W[k*384];
      #pragma unroll
      for (int s = 0; s < 8; ++s) accv[s] += Xs[half*8 + s][k] * wv;
    }
    #pragma unroll
    for (int s = 0; s < 8; ++s)
      giL[(half*8 + s)*384 + j] = accv[s];
  }

  // ---- recurrence weights (pair-split, w[64]/thread, no spill) ----
  int j = tid >> 1, kh = tid & 1;
  float w[64];
  const float4* wrow = (const float4*)(vWhh + (vidx*384 + j)*128 + kh*64);
  #pragma unroll
  for (int k4 = 0; k4 < 16; ++k4) {
    float4 t4 = wrow[k4];
    w[4*k4] = t4.x; w[4*k4+1] = t4.y; w[4*k4+2] = t4.z; w[4*k4+3] = t4.w;
  }
  float bj = vbhh[vidx*384 + j];
  __syncthreads();

  #pragma unroll 1
  for (int v = 0; v < 16; ++v) {
    const float4* h4 = (const float4*)(hsv + kh*64);
    float p0 = 0.f, p1 = 0.f;
    #pragma unroll
    for (int k4 = 0; k4 < 8; ++k4) {
      float4 u0 = h4[k4], u1 = h4[k4+8];
      p0 += w[4*k4   ]*u0.x + w[4*k4+1 ]*u0.y + w[4*k4+2 ]*u0.z + w[4*k4+3 ]*u0.w;
      p1 += w[4*k4+32]*u1.x + w[4*k4+33]*u1.y + w[4*k4+34]*u1.z + w[4*k4+35]*u1.w;
    }
    float part = p0 + p1;
    part += __shfl_xor(part, 1);
    if (kh == 0) gh[j] = bj + ((j < 256) ? giL[v*384 + j] : 0.f) + part;
    __syncthreads();
    if (tid < 128) {
      float r = fsig(gh[tid]);
      float z = fsig(gh[tid+128]);
      float gin = giL[v*384 + 256 + tid];
      float n = ftanh(gin + r*gh[tid+256]);
      hsv[tid] = (1.f - z)*n + z*hsv[tid];
    }
    __syncthreads();
  }
  if (tid < 128) vh[(run*16 + b)*D_ + tid] = hsv[tid];
}

// =====================================================================
// head v4 (pe fused) — verified, unchanged.
// =====================================================================
__global__ __launch_bounds__(256) void k_head(
    const float* __restrict__ vh, const float* __restrict__ Wp,
    const float* __restrict__ bp, float* __restrict__ out)
{
  const int o = blockIdx.x;
  const int tid = threadIdx.x;
  const int b = tid & 15, kc = tid >> 4;
  const int a1[7] = {0,1,2,3,4,8,9};
  const int a2[7] = {-1,5,6,7,-1,-1,-1};
  const float4* wb = (const float4*)(Wp + (size_t)o*896 + kc*56);
  float acc = 0.f;
  #pragma unroll
  for (int i = 0; i < 14; ++i) {
    int cc2 = kc*56 + i*4;
    int s = cc2 >> 7, d0 = cc2 & 127;
    float4 a = *(const float4*)(vh + (a1[s]*16 + b)*D_ + d0);
    int s2 = a2[s];
    if (s2 >= 0) {
      float4 a2v = *(const float4*)(vh + (s2*16 + b)*D_ + d0);
      a.x += a2v.x; a.y += a2v.y; a.z += a2v.z; a.w += a2v.w;
    }
    a.x = fmaxf(a.x, 0.f); a.y = fmaxf(a.y, 0.f);
    a.z = fmaxf(a.z, 0.f); a.w = fmaxf(a.w, 0.f);
    float4 ww = wb[i];
    acc += a.x*ww.x + a.y*ww.y + a.z*ww.z + a.w*ww.w;
  }
  __shared__ float red[16][17];
  red[kc][b] = acc;
  __syncthreads();
  if (tid < 16) {
    float s = 0.f;
    #pragma unroll
    for (int k = 0; k < 16; ++k) s += red[k][tid];
    out[tid*OUT_ + o] = s + bp[o];
  }
}

// =====================================================================
extern "C" void kernel_launch(void* const* d_in, const int* in_sizes, int n_in,
                              void* d_out, int out_size, void* d_ws, size_t ws_size,
                              hipStream_t stream)
{
  (void)in_sizes; (void)n_in; (void)out_size; (void)ws_size;
  const int*   cc   = (const int*)  d_in[0];
  const int*   cp   = (const int*)  d_in[1];
  const int*   cd   = (const int*)  d_in[2];
  const int*   cli  = (const int*)  d_in[3];
  const int*   clv  = (const int*)  d_in[4];
  const int*   cii  = (const int*)  d_in[5];
  const int*   civ  = (const int*)  d_in[6];
  const float* wgt  = (const float*)d_in[7];
  const float* age  = (const float*)d_in[8];
  const float* ec   = (const float*)d_in[9];
  const float* ep   = (const float*)d_in[10];
  const float* ed   = (const float*)d_in[11];
  const float* eli  = (const float*)d_in[12];
  const float* elv  = (const float*)d_in[13];
  const float* eii  = (const float*)d_in[14];
  const float* eiv  = (const float*)d_in[15];
  const float* mWih = (const float*)d_in[16];
  const float* mWhh = (const float*)d_in[17];
  const float* mbih = (const float*)d_in[18];
  const float* mbhh = (const float*)d_in[19];
  const float* vWih = (const float*)d_in[20];
  const float* vWhh = (const float*)d_in[21];
  const float* vbih = (const float*)d_in[22];
  const float* vbhh = (const float*)d_in[23];
  const float* Wself= (const float*)d_in[24];
  const float* Wmsg = (const float*)d_in[25];
  const float* fwW  = (const float*)d_in[26];
  const float* fwB  = (const float*)d_in[27];
  const float* faW  = (const float*)d_in[28];
  const float* faB  = (const float*)d_in[29];
  const float* Wp   = (const float*)d_in[30];
  const float* bp   = (const float*)d_in[31];
  float* out = (float*)d_out;
  float* ws  = (float*)d_ws;

  float* vis   = ws + OFF_VIS;
  short* visb  = (short*)(ws + OFF_VISB);
  short* monb  = (short*)(ws + OFF_MONB);
  short* totb  = (short*)(ws + OFF_TOTB);
  short* w12t  = (short*)(ws + OFF_W12T);
  short* wihb  = (short*)(ws + OFF_WIHB);
  float* wihTv = ws + OFF_WIHTV;
  float* xe    = ws + OFF_XE;
  float* last  = ws + OFF_LAST;
  float* vh    = ws + OFF_VH;

  k_prepvis<<<3392, 256, 0, stream>>>(Wself, Wmsg, mWih, vWih, wgt, age,
                                      fwW, fwB, faW, faB,
                                      cc, cp, cd, ec, ep, ed,
                                      w12t, wihb, wihTv, xe, vis, visb);
  k_mon <<<16384, 128, 0, stream>>>(cli, clv, cii, civ, eli, elv, eii, eiv,
                                    vis, monb, totb);
  k_ggru<<<128, 512, 0, stream>>>(monb, totb, visb, w12t, wihb,
                                  mWhh, mbih, mbhh, last);
  k_vgru<<<160, 768, 0, stream>>>(last, xe, wihTv, vbih, vWhh, vbhh, vh);
  k_head<<<600, 256, 0, stream>>>(vh, Wp, bp, out);
}

// Round 9
// 251.272 us; speedup vs baseline: 1.1644x; 1.1644x over previous
//
#include <hip/hip_runtime.h>
#include <math.h>

#define B_   16
#define V_   16
#define C_   64
#define M_   32
#define CM_  16
#define D_   128
#define OUT_ 600
#define NSEQ 256      // B*V
#define NROW 8192     // B*V*M

typedef __attribute__((ext_vector_type(8))) short bf16x8;
typedef __attribute__((ext_vector_type(4))) short bf16x4;
typedef __attribute__((ext_vector_type(4))) float f32x4;

__device__ __forceinline__ unsigned short f2bf(float x) {
  union { float f; unsigned u; } v; v.f = x;
  unsigned r = v.u + 0x7fff + ((v.u >> 16) & 1);   // RNE
  return (unsigned short)(r >> 16);
}
__device__ __forceinline__ float bf2f(short s) {
  union { unsigned u; float f; } v;
  v.u = ((unsigned)(unsigned short)s) << 16;
  return v.f;
}
// fast sigmoid / tanh: native v_exp + v_rcp (~5 inst), saturate correctly
__device__ __forceinline__ float fsig(float x)  { return __fdividef(1.f, 1.f + __expf(-x)); }
__device__ __forceinline__ float ftanh(float x) { return 1.f - 2.f*__fdividef(1.f, __expf(2.f*x) + 1.f); }

// LDS-only barrier: drains LDS ops for cross-wave visibility but does NOT
// drain vmcnt — in-flight global prefetch loads survive the barrier.
__device__ __forceinline__ void ldsbar() {
  asm volatile("s_waitcnt lgkmcnt(0)" ::: "memory");
  __builtin_amdgcn_s_barrier();
  asm volatile("" ::: "memory");
}

// ---- workspace layout (float units; bf16 arrays are short* views) ----
constexpr int OFF_VISB  = 98304;                           // bf16 [3][256][128]
constexpr int OFF_MONB  = 147456;                          // bf16 [2][8192][128]
constexpr int OFF_W12T  = 2244608;                         // bf16 [8][128n][256k]
constexpr int OFF_WIHB  = 2375680;                         // bf16 [5][384n][128k]
constexpr int OFF_WIHTV = 2498560;                         // fp32 [4][128][384]
constexpr int OFF_XE    = 2695168;                         // fp32 [2][256][128]
constexpr int OFF_LAST  = 27926528;                        // fp32 [8][256][128]
constexpr int OFF_VH    = 29171712;                        // fp32 [10][16][128]

// =====================================================================
// prep+vis+mon merged — THIS ROUND: k_mon's gather work folded in as
// 8192 extra blocks (its vis dependency was removed by moving the
// vsum-add into k_ggru), and totb is gone entirely. 5 -> 4 dispatches.
// =====================================================================
__global__ __launch_bounds__(256) void k_prepvis(
    const float* __restrict__ Wself, const float* __restrict__ Wmsg,
    const float* __restrict__ mWih,  const float* __restrict__ vWih,
    const float* __restrict__ wgt,   const float* __restrict__ age,
    const float* __restrict__ fwW,   const float* __restrict__ fwB,
    const float* __restrict__ faW,   const float* __restrict__ faB,
    const int* __restrict__ cc, const int* __restrict__ cp, const int* __restrict__ cd,
    const float* __restrict__ ec, const float* __restrict__ ep, const float* __restrict__ ed,
    const int* __restrict__ cli, const int* __restrict__ clv,
    const int* __restrict__ cii, const int* __restrict__ civ,
    const float* __restrict__ eli, const float* __restrict__ elv,
    const float* __restrict__ eii, const float* __restrict__ eiv,
    short* __restrict__ w12t, short* __restrict__ wihb,
    float* __restrict__ wihTv, float* __restrict__ xe,
    short* __restrict__ visb, short* __restrict__ monb)
{
  int bx = blockIdx.x, tid = threadIdx.x;
  if (bx < 1024) {                      // w12t[pt][n][k] = bf16 combined
    int lin = bx*256 + tid;             // < 262144
    int pt = lin >> 15, rem = lin & 32767;
    int n = rem >> 8, k = rem & 255;
    float v;
    if (k < 128) v = Wself[pt*16384 + k*128 + n] - Wmsg[pt*16384 + k*128 + n]*(1.f/3.f);
    else         v = Wmsg[pt*16384 + (k-128)*128 + n]*(1.f/3.f);
    w12t[lin] = (short)f2bf(v);
  } else if (bx < 1984) {               // wihb = bf16(mWih) elementwise
    int lin = (bx-1024)*256 + tid;      // < 245760
    wihb[lin] = (short)f2bf(mWih[lin]);
  } else if (bx < 2752) {               // vgru Wih transpose fp32
    int lin = (bx-1984)*256 + tid;      // < 196608
    int g = lin / 49152, rem2 = lin % 49152;
    int k = rem2 / 384, j = rem2 % 384;
    wihTv[lin] = vWih[g*49152 + j*128 + k];
  } else if (bx < 3008) {               // xe for weight / age
    int lin = (bx-2752)*256 + tid;      // < 65536
    int which = lin >> 15, rem2 = lin & 32767;
    int n = rem2 >> 7, d = rem2 & 127;
    float x  = which ? age[n] : wgt[n];
    float Wv = which ? faW[d] : fwW[d];
    float bb = which ? faB[d] : fwB[d];
    xe[lin] = (x != 0.0f) ? (x*Wv + bb) : 0.0f;
  } else if (bx < 3392) {               // visit-event sum pools -> visb
    int idx = (bx-3008)*256 + tid;      // < 98304
    int type = idx >> 15;
    int r = idx & 32767;
    int bv = r >> 7, d = r & 127;
    const int*   codes = (type==0) ? cc : (type==1) ? cp : cd;
    const float* emb   = (type==0) ? ec : (type==1) ? ep : ed;
    float acc = 0.f;
    for (int c = 0; c < C_; ++c) {
      int code = codes[bv*C_ + c];
      acc += emb[code*D_ + d];
    }
    visb[(type*NSEQ + bv)*D_ + d] = (short)f2bf(acc);
  } else {                              // merged k_mon: monb only
    int rowid = (bx-3392)*2 + (tid >> 7);   // 0..16383
    int p = rowid >> 13, bvm = rowid & 8191;
    int d = tid & 127;
    const int* ci = p ? cii : cli;  const int* cv = p ? civ : clv;
    const float* ei = p ? eii : eli; const float* ev = p ? eiv : elv;
    float acc = 0.f;
    #pragma unroll
    for (int c2 = 0; c2 < CM_; ++c2) {
      int iv = ci[bvm*CM_ + c2];
      int vv = cv[bvm*CM_ + c2];
      acc += ei[iv*D_ + d] * ev[vv*D_ + d];
    }
    monb[((size_t)p*NROW + bvm)*D_ + d] = (short)f2bf(acc);
  }
}

// =====================================================================
// FUSED GNN+GI+monitor-GRU (k_ggru v2.1) — reverted to the verified v2
// one-barrier pipeline (round 7), modified: tot rows are computed on
// the fly as mon + vsum (vsum slice preloaded from visb, step-invariant
// registers) — totb array eliminated.
// =====================================================================
__global__ __launch_bounds__(512, 1) void k_ggru(
    const short* __restrict__ monb, const short* __restrict__ visb,
    const short* __restrict__ w12t, const short* __restrict__ wihb,
    const float* __restrict__ mWhh, const float* __restrict__ mbih,
    const float* __restrict__ mbhh, float* __restrict__ last)
{
  const int run  = blockIdx.x >> 4;     // 0..7
  const int pair = blockIdx.x & 15;     // batch b
  const int p = run >> 2, t = run & 3;
  const int g = (run % 4 == 0) ? (run / 4) : (run % 4 + 1);
  const int tid = threadIdx.x;
  const int w = tid >> 6;               // wave 0..7 = hidden slice
  const int lane = tid & 63;
  const int c = lane & 15, q = lane >> 4;
  const int j = w*16 + c;               // hidden index 0..127

  __shared__ short hb[2][4][16][40];            // 10240 B (v8-verified layout)
  __shared__ __align__(16) short Ys[2][16][136];// 8704 B (double-buffered)
  __shared__ __align__(16) short Xl[2][4096];   // 16384 B, XOR-swizzled rows

  for (int idx = tid; idx < 2*4*16*40; idx += 512)
    ((short*)hb)[idx] = 0;

  // ---- stage1 B-frags: w12t[run][n=w*16+c][k], K=256 -> 8 frags ----
  bf16x8 bW12[8];
  #pragma unroll
  for (int kt = 0; kt < 8; ++kt)
    bW12[kt] = *(const bf16x8*)(w12t + (size_t)run*32768 + (size_t)(w*16+c)*256 + kt*32 + q*8);

  // ---- stage2 B-frags: wihb rows gate*128+j ----
  bf16x8 bWih[3][4];
  #pragma unroll
  for (int gate = 0; gate < 3; ++gate)
    #pragma unroll
    for (int kt = 0; kt < 4; ++kt)
      bWih[gate][kt] = *(const bf16x8*)(wihb + ((size_t)g*384 + gate*128 + j)*128 + kt*32 + q*8);

  // ---- stage3 B-frags: mWhh rows gate*128+j (fp32 -> bf16) ----
  bf16x8 bWhh[3][4];
  #pragma unroll
  for (int gate = 0; gate < 3; ++gate) {
    const float* wp = mWhh + ((size_t)g*384 + gate*128 + j)*128 + q*8;
    #pragma unroll
    for (int kt = 0; kt < 4; ++kt) {
      float4 lo = *(const float4*)(wp + kt*32);
      float4 hi = *(const float4*)(wp + kt*32 + 4);
      bf16x8 tt;
      tt[0]=(short)f2bf(lo.x); tt[1]=(short)f2bf(lo.y); tt[2]=(short)f2bf(lo.z); tt[3]=(short)f2bf(lo.w);
      tt[4]=(short)f2bf(hi.x); tt[5]=(short)f2bf(hi.y); tt[6]=(short)f2bf(hi.z); tt[7]=(short)f2bf(hi.w);
      bWhh[gate][kt] = tt;
    }
  }
  const float bs0 = mbih[g*384 +       j] + mbhh[g*384 +       j];
  const float bs1 = mbih[g*384 + 128 + j] + mbhh[g*384 + 128 + j];
  const float bi2 = mbih[g*384 + 256 + j];
  const float bh2 = mbhh[g*384 + 256 + j];

  // ---- X staging mapping: thread (r = tid>>5, u = tid&31) ----
  // cols 0-127 = feat (mon or vis[t-1]); cols 128-255 = tot = mon + vsum
  const int xr_ = tid >> 5, xu = tid & 31;
  const int bv = pair*16 + xr_;
  const bool istot = (xu >= 16);
  const short* fsrc;
  int fstride;                                   // shorts per step
  float vsf[8] = {0.f,0.f,0.f,0.f,0.f,0.f,0.f,0.f};
  if (!istot) {
    if (t == 0) { fsrc = monb + ((size_t)p*NROW + (size_t)bv*32)*128 + xu*8; fstride = 128; }
    else        { fsrc = visb + ((size_t)(t-1)*NSEQ + bv)*128 + xu*8;        fstride = 0;   }
  } else {
    fsrc = monb + ((size_t)p*NROW + (size_t)bv*32)*128 + (xu-16)*8;          fstride = 128;
    #pragma unroll
    for (int i = 0; i < 8; ++i)
      vsf[i] = bf2f(visb[(0*NSEQ + bv)*128 + (xu-16)*8 + i])
             + bf2f(visb[(1*NSEQ + bv)*128 + (xu-16)*8 + i])
             + bf2f(visb[(2*NSEQ + bv)*128 + (xu-16)*8 + i]);
  }
  auto fixtot = [&](bf16x8 x) -> bf16x8 {
    if (istot) {
      #pragma unroll
      for (int i = 0; i < 8; ++i) x[i] = (short)f2bf(bf2f(x[i]) + vsf[i]);
    }
    return x;
  };
  const int xdofs = xr_*256 + (((xu*16) ^ ((xr_&7)<<4)) >> 1);   // shorts
  short* xdst0 = &Xl[0][xdofs];
  short* xdst1 = &Xl[1][xdofs];

  // prologue: X(0) -> Xl[0], X(1) -> Xl[1]
  {
    bf16x8 x0 = fixtot(*(const bf16x8*)fsrc);
    bf16x8 x1 = fixtot(*(const bf16x8*)(fsrc + fstride));
    *(bf16x8*)xdst0 = x0;
    *(bf16x8*)xdst1 = x1;
  }
  float hf[4] = {0.f,0.f,0.f,0.f};
  const int ktw = w >> 1;               // j>>5
  const int kkw = (w & 1)*16 + c;       // j&31
  ldsbar();   // hb zero + X(0), X(1) visible

  // prologue stage1: Y(0) from Xl[0] -> Ys[0]
  {
    const char* xbase = (const char*)&Xl[0][0];
    f32x4 accY = (f32x4){0.f,0.f,0.f,0.f};
    #pragma unroll
    for (int kt = 0; kt < 8; ++kt) {
      bf16x8 aX = *(const bf16x8*)(xbase + c*512 + ((kt*64 + q*16) ^ ((c&7)<<4)));
      accY = __builtin_amdgcn_mfma_f32_16x16x32_bf16(aX, bW12[kt], accY, 0, 0, 0);
    }
    #pragma unroll
    for (int reg = 0; reg < 4; ++reg)
      Ys[0][q*4 + reg][w*16 + c] = (short)f2bf(fmaxf(accY[reg], 0.f));
  }
  ldsbar();   // Ys[0] ready

  #pragma unroll 1
  for (int m = 0; m < 32; ++m) {
    const int cur = m & 1, nxt = cur ^ 1;

    // issue X(m+2) global load early (hidden under this step)
    bf16x8 xnext;
    if (m < 30) xnext = *(const bf16x8*)(fsrc + (size_t)(m+2)*fstride);

    // ---- phase A: stage1 for step m+1: Y(m+1) from Xl[nxt] ----
    f32x4 accY = (f32x4){0.f,0.f,0.f,0.f};
    if (m < 31) {
      const char* xbase = (const char*)&Xl[nxt][0];
      #pragma unroll
      for (int kt = 0; kt < 8; ++kt) {
        bf16x8 aX = *(const bf16x8*)(xbase + c*512 + ((kt*64 + q*16) ^ ((c&7)<<4)));
        accY = __builtin_amdgcn_mfma_f32_16x16x32_bf16(aX, bW12[kt], accY, 0, 0, 0);
      }
    }

    // ---- phase B: stage2+3 gate pre-acts from Ys[cur], hb[cur] ----
    bf16x8 ah[4], a2[4];
    #pragma unroll
    for (int kt = 0; kt < 4; ++kt) {
      ah[kt] = *(const bf16x8*)&hb[cur][kt][c][q*8];
      a2[kt] = *(const bf16x8*)&Ys[cur][c][kt*32 + q*8];
    }
    f32x4 acc0 = (f32x4){0.f,0.f,0.f,0.f};
    f32x4 acc1 = (f32x4){0.f,0.f,0.f,0.f};
    f32x4 aG2  = (f32x4){0.f,0.f,0.f,0.f};
    f32x4 aH2  = (f32x4){0.f,0.f,0.f,0.f};
    #pragma unroll
    for (int kt = 0; kt < 4; ++kt) {
      acc0 = __builtin_amdgcn_mfma_f32_16x16x32_bf16(ah[kt], bWhh[0][kt], acc0, 0, 0, 0);
      acc1 = __builtin_amdgcn_mfma_f32_16x16x32_bf16(ah[kt], bWhh[1][kt], acc1, 0, 0, 0);
      aH2  = __builtin_amdgcn_mfma_f32_16x16x32_bf16(ah[kt], bWhh[2][kt], aH2,  0, 0, 0);
    }
    #pragma unroll
    for (int kt = 0; kt < 4; ++kt) {
      acc0 = __builtin_amdgcn_mfma_f32_16x16x32_bf16(a2[kt], bWih[0][kt], acc0, 0, 0, 0);
      acc1 = __builtin_amdgcn_mfma_f32_16x16x32_bf16(a2[kt], bWih[1][kt], acc1, 0, 0, 0);
      aG2  = __builtin_amdgcn_mfma_f32_16x16x32_bf16(a2[kt], bWih[2][kt], aG2,  0, 0, 0);
    }

    // write Y(m+1) into Ys[nxt] (read at step m+1, after the barrier)
    if (m < 31) {
      #pragma unroll
      for (int reg = 0; reg < 4; ++reg)
        Ys[nxt][q*4 + reg][w*16 + c] = (short)f2bf(fmaxf(accY[reg], 0.f));
    }
    // write X(m+2) into Xl[cur] (its old contents consumed at step m-1)
    if (m < 30) *(bf16x8*)(cur ? xdst1 : xdst0) = fixtot(xnext);

    // ---- lane-local GRU activation: (seq = q*4+reg, this j) ----
    #pragma unroll
    for (int reg = 0; reg < 4; ++reg) {
      float rr = fsig(acc0[reg] + bs0);
      float zz = fsig(acc1[reg] + bs1);
      float nn = ftanh(aG2[reg] + bi2 + rr*(aH2[reg] + bh2));
      float hnew = (1.f - zz)*nn + zz*hf[reg];
      hf[reg] = hnew;
      hb[nxt][ktw][q*4 + reg][kkw] = (short)f2bf(hnew);
    }
    ldsbar();   // ONE barrier: Ys[nxt] + hb[nxt] + Xl[cur] visible for m+1
  }

  #pragma unroll
  for (int reg = 0; reg < 4; ++reg)
    last[((size_t)run*NSEQ + pair*16 + q*4 + reg)*D_ + j] = hf[reg];
}

// =====================================================================
// visit-level GRU v3 (vgi fused) — verified, unchanged.
// =====================================================================
__global__ __launch_bounds__(768) void k_vgru(
    const float* __restrict__ last, const float* __restrict__ xe,
    const float* __restrict__ wihTv, const float* __restrict__ vbih,
    const float* __restrict__ vWhh, const float* __restrict__ vbhh,
    float* __restrict__ vh)
{
  int run = blockIdx.x >> 4, b = blockIdx.x & 15;
  int tid = threadIdx.x;
  int vidx = (run < 4) ? 0 : (run < 8) ? 1 : (run - 6);

  __shared__ float Xs[16][128];          // 8 KB
  __shared__ float giL[16*384];          // 24 KB
  __shared__ __align__(16) float hsv[128];
  __shared__ float gh[384];

  const float* X = (run < 8) ? (last + ((size_t)run*NSEQ + b*16)*D_)
                             : (xe + ((size_t)(run-8)*NSEQ + b*16)*D_);
  for (int idx = tid; idx < 2048; idx += 768)
    ((float*)Xs)[idx] = X[idx];
  if (tid < 128) hsv[tid] = 0.f;
  __syncthreads();

  // ---- gi precompute into LDS: thread (half, j) does 8 visits ----
  {
    int half = (tid >= 384) ? 1 : 0;
    int j = tid - half*384;
    float accv[8];
    float bias = vbih[vidx*384 + j];
    #pragma unroll
    for (int s = 0; s < 8; ++s) accv[s] = bias;
    const float* W = wihTv + vidx*49152 + j;
    #pragma unroll 4
    for (int k = 0; k < 128; ++k) {
      float wv = W[k*384];
      #pragma unroll
      for (int s = 0; s < 8; ++s) accv[s] += Xs[half*8 + s][k] * wv;
    }
    #pragma unroll
    for (int s = 0; s < 8; ++s)
      giL[(half*8 + s)*384 + j] = accv[s];
  }

  // ---- recurrence weights (pair-split, w[64]/thread, no spill) ----
  int j = tid >> 1, kh = tid & 1;
  float w[64];
  const float4* wrow = (const float4*)(vWhh + (vidx*384 + j)*128 + kh*64);
  #pragma unroll
  for (int k4 = 0; k4 < 16; ++k4) {
    float4 t4 = wrow[k4];
    w[4*k4] = t4.x; w[4*k4+1] = t4.y; w[4*k4+2] = t4.z; w[4*k4+3] = t4.w;
  }
  float bj = vbhh[vidx*384 + j];
  __syncthreads();

  #pragma unroll 1
  for (int v = 0; v < 16; ++v) {
    const float4* h4 = (const float4*)(hsv + kh*64);
    float p0 = 0.f, p1 = 0.f;
    #pragma unroll
    for (int k4 = 0; k4 < 8; ++k4) {
      float4 u0 = h4[k4], u1 = h4[k4+8];
      p0 += w[4*k4   ]*u0.x + w[4*k4+1 ]*u0.y + w[4*k4+2 ]*u0.z + w[4*k4+3 ]*u0.w;
      p1 += w[4*k4+32]*u1.x + w[4*k4+33]*u1.y + w[4*k4+34]*u1.z + w[4*k4+35]*u1.w;
    }
    float part = p0 + p1;
    part += __shfl_xor(part, 1);
    if (kh == 0) gh[j] = bj + ((j < 256) ? giL[v*384 + j] : 0.f) + part;
    __syncthreads();
    if (tid < 128) {
      float r = fsig(gh[tid]);
      float z = fsig(gh[tid+128]);
      float gin = giL[v*384 + 256 + tid];
      float n = ftanh(gin + r*gh[tid+256]);
      hsv[tid] = (1.f - z)*n + z*hsv[tid];
    }
    __syncthreads();
  }
  if (tid < 128) vh[(run*16 + b)*D_ + tid] = hsv[tid];
}

// =====================================================================
// head v4 (pe fused) — verified, unchanged.
// =====================================================================
__global__ __launch_bounds__(256) void k_head(
    const float* __restrict__ vh, const float* __restrict__ Wp,
    const float* __restrict__ bp, float* __restrict__ out)
{
  const int o = blockIdx.x;
  const int tid = threadIdx.x;
  const int b = tid & 15, kc = tid >> 4;
  const int a1[7] = {0,1,2,3,4,8,9};
  const int a2[7] = {-1,5,6,7,-1,-1,-1};
  const float4* wb = (const float4*)(Wp + (size_t)o*896 + kc*56);
  float acc = 0.f;
  #pragma unroll
  for (int i = 0; i < 14; ++i) {
    int cc2 = kc*56 + i*4;
    int s = cc2 >> 7, d0 = cc2 & 127;
    float4 a = *(const float4*)(vh + (a1[s]*16 + b)*D_ + d0);
    int s2 = a2[s];
    if (s2 >= 0) {
      float4 a2v = *(const float4*)(vh + (s2*16 + b)*D_ + d0);
      a.x += a2v.x; a.y += a2v.y; a.z += a2v.z; a.w += a2v.w;
    }
    a.x = fmaxf(a.x, 0.f); a.y = fmaxf(a.y, 0.f);
    a.z = fmaxf(a.z, 0.f); a.w = fmaxf(a.w, 0.f);
    float4 ww = wb[i];
    acc += a.x*ww.x + a.y*ww.y + a.z*ww.z + a.w*ww.w;
  }
  __shared__ float red[16][17];
  red[kc][b] = acc;
  __syncthreads();
  if (tid < 16) {
    float s = 0.f;
    #pragma unroll
    for (int k = 0; k < 16; ++k) s += red[k][tid];
    out[tid*OUT_ + o] = s + bp[o];
  }
}

// =====================================================================
extern "C" void kernel_launch(void* const* d_in, const int* in_sizes, int n_in,
                              void* d_out, int out_size, void* d_ws, size_t ws_size,
                              hipStream_t stream)
{
  (void)in_sizes; (void)n_in; (void)out_size; (void)ws_size;
  const int*   cc   = (const int*)  d_in[0];
  const int*   cp   = (const int*)  d_in[1];
  const int*   cd   = (const int*)  d_in[2];
  const int*   cli  = (const int*)  d_in[3];
  const int*   clv  = (const int*)  d_in[4];
  const int*   cii  = (const int*)  d_in[5];
  const int*   civ  = (const int*)  d_in[6];
  const float* wgt  = (const float*)d_in[7];
  const float* age  = (const float*)d_in[8];
  const float* ec   = (const float*)d_in[9];
  const float* ep   = (const float*)d_in[10];
  const float* ed   = (const float*)d_in[11];
  const float* eli  = (const float*)d_in[12];
  const float* elv  = (const float*)d_in[13];
  const float* eii  = (const float*)d_in[14];
  const float* eiv  = (const float*)d_in[15];
  const float* mWih = (const float*)d_in[16];
  const float* mWhh = (const float*)d_in[17];
  const float* mbih = (const float*)d_in[18];
  const float* mbhh = (const float*)d_in[19];
  const float* vWih = (const float*)d_in[20];
  const float* vWhh = (const float*)d_in[21];
  const float* vbih = (const float*)d_in[22];
  const float* vbhh = (const float*)d_in[23];
  const float* Wself= (const float*)d_in[24];
  const float* Wmsg = (const float*)d_in[25];
  const float* fwW  = (const float*)d_in[26];
  const float* fwB  = (const float*)d_in[27];
  const float* faW  = (const float*)d_in[28];
  const float* faB  = (const float*)d_in[29];
  const float* Wp   = (const float*)d_in[30];
  const float* bp   = (const float*)d_in[31];
  float* out = (float*)d_out;
  float* ws  = (float*)d_ws;

  short* visb  = (short*)(ws + OFF_VISB);
  short* monb  = (short*)(ws + OFF_MONB);
  short* w12t  = (short*)(ws + OFF_W12T);
  short* wihb  = (short*)(ws + OFF_WIHB);
  float* wihTv = ws + OFF_WIHTV;
  float* xe    = ws + OFF_XE;
  float* last  = ws + OFF_LAST;
  float* vh    = ws + OFF_VH;

  k_prepvis<<<11584, 256, 0, stream>>>(Wself, Wmsg, mWih, vWih, wgt, age,
                                       fwW, fwB, faW, faB,
                                       cc, cp, cd, ec, ep, ed,
                                       cli, clv, cii, civ, eli, elv, eii, eiv,
                                       w12t, wihb, wihTv, xe, visb, monb);
  k_ggru<<<128, 512, 0, stream>>>(monb, visb, w12t, wihb,
                                  mWhh, mbih, mbhh, last);
  k_vgru<<<160, 768, 0, stream>>>(last, xe, wihTv, vbih, vWhh, vbhh, vh);
  k_head<<<600, 256, 0, stream>>>(vh, Wp, bp, out);
}

// Round 11
// 244.797 us; speedup vs baseline: 1.1952x; 1.0265x over previous
//
#include <hip/hip_runtime.h>
#include <math.h>

#define B_   16
#define V_   16
#define C_   64
#define M_   32
#define CM_  16
#define D_   128
#define OUT_ 600
#define NSEQ 256      // B*V
#define NROW 8192     // B*V*M

typedef __attribute__((ext_vector_type(8))) short bf16x8;
typedef __attribute__((ext_vector_type(4))) short bf16x4;
typedef __attribute__((ext_vector_type(4))) float f32x4;

__device__ __forceinline__ unsigned short f2bf(float x) {
  union { float f; unsigned u; } v; v.f = x;
  unsigned r = v.u + 0x7fff + ((v.u >> 16) & 1);   // RNE
  return (unsigned short)(r >> 16);
}
__device__ __forceinline__ float bf2f(short s) {
  union { unsigned u; float f; } v;
  v.u = ((unsigned)(unsigned short)s) << 16;
  return v.f;
}
// fast sigmoid / tanh: native v_exp + v_rcp (~5 inst), saturate correctly
__device__ __forceinline__ float fsig(float x)  { return __fdividef(1.f, 1.f + __expf(-x)); }
__device__ __forceinline__ float ftanh(float x) { return 1.f - 2.f*__fdividef(1.f, __expf(2.f*x) + 1.f); }

// LDS-only barrier: drains LDS ops for cross-wave visibility but does NOT
// drain vmcnt — in-flight global prefetch loads survive the barrier.
__device__ __forceinline__ void ldsbar() {
  asm volatile("s_waitcnt lgkmcnt(0)" ::: "memory");
  __builtin_amdgcn_s_barrier();
  asm volatile("" ::: "memory");
}

// ---- workspace layout (float units; bf16 arrays are short* views) ----
constexpr int OFF_VISB  = 98304;                           // bf16 [3][256][128]
constexpr int OFF_MONB  = 147456;                          // bf16 [2][8192][128]
constexpr int OFF_W12T  = 2244608;                         // bf16 [8][128n][256k]
constexpr int OFF_WIHB  = 2375680;                         // bf16 [5][384n][128k]
constexpr int OFF_WIHTV = 2498560;                         // fp32 [4][128][384]
constexpr int OFF_XE    = 2695168;                         // fp32 [2][256][128]
constexpr int OFF_LAST  = 27926528;                        // fp32 [8][256][128]
constexpr int OFF_VH    = 29171712;                        // fp32 [10][16][128]

// =====================================================================
// prep+vis+mon merged — verified round 8, unchanged.
// =====================================================================
__global__ __launch_bounds__(256) void k_prepvis(
    const float* __restrict__ Wself, const float* __restrict__ Wmsg,
    const float* __restrict__ mWih,  const float* __restrict__ vWih,
    const float* __restrict__ wgt,   const float* __restrict__ age,
    const float* __restrict__ fwW,   const float* __restrict__ fwB,
    const float* __restrict__ faW,   const float* __restrict__ faB,
    const int* __restrict__ cc, const int* __restrict__ cp, const int* __restrict__ cd,
    const float* __restrict__ ec, const float* __restrict__ ep, const float* __restrict__ ed,
    const int* __restrict__ cli, const int* __restrict__ clv,
    const int* __restrict__ cii, const int* __restrict__ civ,
    const float* __restrict__ eli, const float* __restrict__ elv,
    const float* __restrict__ eii, const float* __restrict__ eiv,
    short* __restrict__ w12t, short* __restrict__ wihb,
    float* __restrict__ wihTv, float* __restrict__ xe,
    short* __restrict__ visb, short* __restrict__ monb)
{
  int bx = blockIdx.x, tid = threadIdx.x;
  if (bx < 1024) {                      // w12t[pt][n][k] = bf16 combined
    int lin = bx*256 + tid;             // < 262144
    int pt = lin >> 15, rem = lin & 32767;
    int n = rem >> 8, k = rem & 255;
    float v;
    if (k < 128) v = Wself[pt*16384 + k*128 + n] - Wmsg[pt*16384 + k*128 + n]*(1.f/3.f);
    else         v = Wmsg[pt*16384 + (k-128)*128 + n]*(1.f/3.f);
    w12t[lin] = (short)f2bf(v);
  } else if (bx < 1984) {               // wihb = bf16(mWih) elementwise
    int lin = (bx-1024)*256 + tid;      // < 245760
    wihb[lin] = (short)f2bf(mWih[lin]);
  } else if (bx < 2752) {               // vgru Wih transpose fp32
    int lin = (bx-1984)*256 + tid;      // < 196608
    int g = lin / 49152, rem2 = lin % 49152;
    int k = rem2 / 384, j = rem2 % 384;
    wihTv[lin] = vWih[g*49152 + j*128 + k];
  } else if (bx < 3008) {               // xe for weight / age
    int lin = (bx-2752)*256 + tid;      // < 65536
    int which = lin >> 15, rem2 = lin & 32767;
    int n = rem2 >> 7, d = rem2 & 127;
    float x  = which ? age[n] : wgt[n];
    float Wv = which ? faW[d] : fwW[d];
    float bb = which ? faB[d] : fwB[d];
    xe[lin] = (x != 0.0f) ? (x*Wv + bb) : 0.0f;
  } else if (bx < 3392) {               // visit-event sum pools -> visb
    int idx = (bx-3008)*256 + tid;      // < 98304
    int type = idx >> 15;
    int r = idx & 32767;
    int bv = r >> 7, d = r & 127;
    const int*   codes = (type==0) ? cc : (type==1) ? cp : cd;
    const float* emb   = (type==0) ? ec : (type==1) ? ep : ed;
    float acc = 0.f;
    for (int c = 0; c < C_; ++c) {
      int code = codes[bv*C_ + c];
      acc += emb[code*D_ + d];
    }
    visb[(type*NSEQ + bv)*D_ + d] = (short)f2bf(acc);
  } else {                              // merged k_mon: monb only
    int rowid = (bx-3392)*2 + (tid >> 7);   // 0..16383
    int p = rowid >> 13, bvm = rowid & 8191;
    int d = tid & 127;
    const int* ci = p ? cii : cli;  const int* cv = p ? civ : clv;
    const float* ei = p ? eii : eli; const float* ev = p ? eiv : elv;
    float acc = 0.f;
    #pragma unroll
    for (int c2 = 0; c2 < CM_; ++c2) {
      int iv = ci[bvm*CM_ + c2];
      int vv = cv[bvm*CM_ + c2];
      acc += ei[iv*D_ + d] * ev[vv*D_ + d];
    }
    monb[((size_t)p*NROW + bvm)*D_ + d] = (short)f2bf(acc);
  }
}

// =====================================================================
// FUSED GNN+GI+monitor-GRU (k_ggru v2.2) — RERUN of round 9 (bench
// aborted with no counters; full OOB/race/alignment audit found no
// defect — disambiguating infra flake vs real fault).
// Y(m) = relu( step-invariant Cpre + mon(m)@Ws^T ) where
//   t==0: Cpre = vsum@W2^T,            Ws = Wself (exact f32->bf16)
//   t>0 : Cpre = vis@W1^T + vsum@W2^T, Ws = W2
// Steady loop: stage1 = 4 MFMAs (was 8), staging = mon row only,
// no fixtot VALU. One-barrier pipeline otherwise as verified v2.
// =====================================================================
__global__ __launch_bounds__(512, 1) void k_ggru(
    const short* __restrict__ monb, const short* __restrict__ visb,
    const short* __restrict__ w12t, const short* __restrict__ wihb,
    const float* __restrict__ Wself, const float* __restrict__ mWhh,
    const float* __restrict__ mbih, const float* __restrict__ mbhh,
    float* __restrict__ last)
{
  const int run  = blockIdx.x >> 4;     // 0..7
  const int pair = blockIdx.x & 15;     // batch b
  const int p = run >> 2, t = run & 3;
  const int g = (run % 4 == 0) ? (run / 4) : (run % 4 + 1);
  const int tid = threadIdx.x;
  const int w = tid >> 6;               // wave 0..7 = hidden slice
  const int lane = tid & 63;
  const int c = lane & 15, q = lane >> 4;
  const int j = w*16 + c;               // hidden index 0..127

  __shared__ short hb[2][4][16][40];            // 10240 B (v8-verified layout)
  __shared__ __align__(16) short Ys[2][16][136];// 8704 B (double-buffered)
  __shared__ __align__(16) short Xl[2][2048];   // 8192 B (mon rows only)

  for (int idx = tid; idx < 2*4*16*40; idx += 512)
    ((short*)hb)[idx] = 0;

  // ---- W12 frags (prologue use; W2 half also steady for t>0) ----
  bf16x8 bW12[8];
  #pragma unroll
  for (int kt = 0; kt < 8; ++kt)
    bW12[kt] = *(const bf16x8*)(w12t + (size_t)run*32768 + (size_t)j*256 + kt*32 + q*8);

  // ---- steady stage1 B-frags: Ws = (t==0 ? Wself exact : W2) ----
  bf16x8 bWs[4];
  if (t == 0) {
    const float* wsp = Wself + (size_t)run*16384 + j;    // + k*128
    #pragma unroll
    for (int kt = 0; kt < 4; ++kt) {
      bf16x8 tt;
      #pragma unroll
      for (int i = 0; i < 8; ++i)
        tt[i] = (short)f2bf(wsp[(kt*32 + q*8 + i)*128]);
      bWs[kt] = tt;
    }
  } else {
    #pragma unroll
    for (int kt = 0; kt < 4; ++kt) bWs[kt] = bW12[kt+4];
  }

  // ---- Cpre: step-invariant part of Y, computed once ----
  // A-frag rows = seqs: bv_c = pair*16 + c
  f32x4 Cpre = (f32x4){0.f,0.f,0.f,0.f};
  {
    const int bvc = pair*16 + c;
    #pragma unroll
    for (int kt = 0; kt < 4; ++kt) {
      const int ko = kt*32 + q*8;
      bf16x8 v0 = *(const bf16x8*)(visb + (size_t)(0*NSEQ + bvc)*128 + ko);
      bf16x8 v1 = *(const bf16x8*)(visb + (size_t)(1*NSEQ + bvc)*128 + ko);
      bf16x8 v2 = *(const bf16x8*)(visb + (size_t)(2*NSEQ + bvc)*128 + ko);
      bf16x8 vs;
      #pragma unroll
      for (int i = 0; i < 8; ++i)
        vs[i] = (short)f2bf(bf2f(v0[i]) + bf2f(v1[i]) + bf2f(v2[i]));
      Cpre = __builtin_amdgcn_mfma_f32_16x16x32_bf16(vs, bW12[kt+4], Cpre, 0, 0, 0);
    }
    if (t > 0) {
      #pragma unroll
      for (int kt = 0; kt < 4; ++kt) {
        const int ko = kt*32 + q*8;
        bf16x8 fv = *(const bf16x8*)(visb + (size_t)((t-1)*NSEQ + bvc)*128 + ko);
        Cpre = __builtin_amdgcn_mfma_f32_16x16x32_bf16(fv, bW12[kt], Cpre, 0, 0, 0);
      }
    }
  }

  // ---- stage2 B-frags: wihb rows gate*128+j ----
  bf16x8 bWih[3][4];
  #pragma unroll
  for (int gate = 0; gate < 3; ++gate)
    #pragma unroll
    for (int kt = 0; kt < 4; ++kt)
      bWih[gate][kt] = *(const bf16x8*)(wihb + ((size_t)g*384 + gate*128 + j)*128 + kt*32 + q*8);

  // ---- stage3 B-frags: mWhh rows gate*128+j (fp32 -> bf16) ----
  bf16x8 bWhh[3][4];
  #pragma unroll
  for (int gate = 0; gate < 3; ++gate) {
    const float* wp = mWhh + ((size_t)g*384 + gate*128 + j)*128 + q*8;
    #pragma unroll
    for (int kt = 0; kt < 4; ++kt) {
      float4 lo = *(const float4*)(wp + kt*32);
      float4 hi = *(const float4*)(wp + kt*32 + 4);
      bf16x8 tt;
      tt[0]=(short)f2bf(lo.x); tt[1]=(short)f2bf(lo.y); tt[2]=(short)f2bf(lo.z); tt[3]=(short)f2bf(lo.w);
      tt[4]=(short)f2bf(hi.x); tt[5]=(short)f2bf(hi.y); tt[6]=(short)f2bf(hi.z); tt[7]=(short)f2bf(hi.w);
      bWhh[gate][kt] = tt;
    }
  }
  const float bs0 = mbih[g*384 +       j] + mbhh[g*384 +       j];
  const float bs1 = mbih[g*384 + 128 + j] + mbhh[g*384 + 128 + j];
  const float bi2 = mbih[g*384 + 256 + j];
  const float bh2 = mbhh[g*384 + 256 + j];

  // ---- mon staging: 256 threads, 16 rows x 16 slots x 8 shorts ----
  const bool stg = (tid < 256);
  const int xr_ = (tid >> 4) & 15, xu = tid & 15;   // valid when stg
  const int bv = pair*16 + xr_;
  const short* fsrc = monb + ((size_t)p*NROW + (size_t)bv*32)*128 + xu*8;
  const int xdofs = xr_*128 + (((xu*16) ^ ((xr_&7)<<4)) >> 1);   // shorts
  short* xdst0 = &Xl[0][xdofs];
  short* xdst1 = &Xl[1][xdofs];

  // prologue: mon(0) -> Xl[0], mon(1) -> Xl[1]
  if (stg) {
    *(bf16x8*)xdst0 = *(const bf16x8*)fsrc;
    *(bf16x8*)xdst1 = *(const bf16x8*)(fsrc + 128);
  }
  float hf[4] = {0.f,0.f,0.f,0.f};
  const int ktw = w >> 1;               // j>>5
  const int kkw = (w & 1)*16 + c;       // j&31
  ldsbar();   // hb zero + X(0), X(1) visible

  // prologue stage1: Y(0) from Xl[0] -> Ys[0]
  {
    const char* xbase = (const char*)&Xl[0][0];
    f32x4 accY = Cpre;
    #pragma unroll
    for (int kt = 0; kt < 4; ++kt) {
      bf16x8 aX = *(const bf16x8*)(xbase + c*256 + ((kt*64 + q*16) ^ ((c&7)<<4)));
      accY = __builtin_amdgcn_mfma_f32_16x16x32_bf16(aX, bWs[kt], accY, 0, 0, 0);
    }
    #pragma unroll
    for (int reg = 0; reg < 4; ++reg)
      Ys[0][q*4 + reg][w*16 + c] = (short)f2bf(fmaxf(accY[reg], 0.f));
  }
  ldsbar();   // Ys[0] ready

  #pragma unroll 1
  for (int m = 0; m < 32; ++m) {
    const int cur = m & 1, nxt = cur ^ 1;

    // issue mon(m+2) global load early (hidden under this step)
    bf16x8 xnext;
    if (stg && m < 30) xnext = *(const bf16x8*)(fsrc + (size_t)(m+2)*128);

    // ---- phase A: stage1 for step m+1: Y(m+1) = Cpre + mon@Ws^T ----
    f32x4 accY = Cpre;
    if (m < 31) {
      const char* xbase = (const char*)&Xl[nxt][0];
      #pragma unroll
      for (int kt = 0; kt < 4; ++kt) {
        bf16x8 aX = *(const bf16x8*)(xbase + c*256 + ((kt*64 + q*16) ^ ((c&7)<<4)));
        accY = __builtin_amdgcn_mfma_f32_16x16x32_bf16(aX, bWs[kt], accY, 0, 0, 0);
      }
    }

    // ---- phase B: stage2+3 gate pre-acts from Ys[cur], hb[cur] ----
    bf16x8 ah[4], a2[4];
    #pragma unroll
    for (int kt = 0; kt < 4; ++kt) {
      ah[kt] = *(const bf16x8*)&hb[cur][kt][c][q*8];
      a2[kt] = *(const bf16x8*)&Ys[cur][c][kt*32 + q*8];
    }
    f32x4 acc0 = (f32x4){0.f,0.f,0.f,0.f};
    f32x4 acc1 = (f32x4){0.f,0.f,0.f,0.f};
    f32x4 aG2  = (f32x4){0.f,0.f,0.f,0.f};
    f32x4 aH2  = (f32x4){0.f,0.f,0.f,0.f};
    #pragma unroll
    for (int kt = 0; kt < 4; ++kt) {
      acc0 = __builtin_amdgcn_mfma_f32_16x16x32_bf16(ah[kt], bWhh[0][kt], acc0, 0, 0, 0);
      acc1 = __builtin_amdgcn_mfma_f32_16x16x32_bf16(ah[kt], bWhh[1][kt], acc1, 0, 0, 0);
      aH2  = __builtin_amdgcn_mfma_f32_16x16x32_bf16(ah[kt], bWhh[2][kt], aH2,  0, 0, 0);
    }
    #pragma unroll
    for (int kt = 0; kt < 4; ++kt) {
      acc0 = __builtin_amdgcn_mfma_f32_16x16x32_bf16(a2[kt], bWih[0][kt], acc0, 0, 0, 0);
      acc1 = __builtin_amdgcn_mfma_f32_16x16x32_bf16(a2[kt], bWih[1][kt], acc1, 0, 0, 0);
      aG2  = __builtin_amdgcn_mfma_f32_16x16x32_bf16(a2[kt], bWih[2][kt], aG2,  0, 0, 0);
    }

    // write Y(m+1) into Ys[nxt] (read at step m+1, after the barrier)
    if (m < 31) {
      #pragma unroll
      for (int reg = 0; reg < 4; ++reg)
        Ys[nxt][q*4 + reg][w*16 + c] = (short)f2bf(fmaxf(accY[reg], 0.f));
    }
    // write mon(m+2) into Xl[cur] (its old contents consumed at step m-1)
    if (stg && m < 30) *(bf16x8*)(cur ? xdst1 : xdst0) = xnext;

    // ---- lane-local GRU activation: (seq = q*4+reg, this j) ----
    #pragma unroll
    for (int reg = 0; reg < 4; ++reg) {
      float rr = fsig(acc0[reg] + bs0);
      float zz = fsig(acc1[reg] + bs1);
      float nn = ftanh(aG2[reg] + bi2 + rr*(aH2[reg] + bh2));
      float hnew = (1.f - zz)*nn + zz*hf[reg];
      hf[reg] = hnew;
      hb[nxt][ktw][q*4 + reg][kkw] = (short)f2bf(hnew);
    }
    ldsbar();   // ONE barrier: Ys[nxt] + hb[nxt] + Xl[cur] visible for m+1
  }

  #pragma unroll
  for (int reg = 0; reg < 4; ++reg)
    last[((size_t)run*NSEQ + pair*16 + q*4 + reg)*D_ + j] = hf[reg];
}

// =====================================================================
// visit-level GRU v3 (vgi fused) — verified, unchanged.
// =====================================================================
__global__ __launch_bounds__(768) void k_vgru(
    const float* __restrict__ last, const float* __restrict__ xe,
    const float* __restrict__ wihTv, const float* __restrict__ vbih,
    const float* __restrict__ vWhh, const float* __restrict__ vbhh,
    float* __restrict__ vh)
{
  int run = blockIdx.x >> 4, b = blockIdx.x & 15;
  int tid = threadIdx.x;
  int vidx = (run < 4) ? 0 : (run < 8) ? 1 : (run - 6);

  __shared__ float Xs[16][128];          // 8 KB
  __shared__ float giL[16*384];          // 24 KB
  __shared__ __align__(16) float hsv[128];
  __shared__ float gh[384];

  const float* X = (run < 8) ? (last + ((size_t)run*NSEQ + b*16)*D_)
                             : (xe + ((size_t)(run-8)*NSEQ + b*16)*D_);
  for (int idx = tid; idx < 2048; idx += 768)
    ((float*)Xs)[idx] = X[idx];
  if (tid < 128) hsv[tid] = 0.f;
  __syncthreads();

  // ---- gi precompute into LDS: thread (half, j) does 8 visits ----
  {
    int half = (tid >= 384) ? 1 : 0;
    int j = tid - half*384;
    float accv[8];
    float bias = vbih[vidx*384 + j];
    #pragma unroll
    for (int s = 0; s < 8; ++s) accv[s] = bias;
    const float* W = wihTv + vidx*49152 + j;
    #pragma unroll 4
    for (int k = 0; k < 128; ++k) {
      float wv = W[k*384];
      #pragma unroll
      for (int s = 0; s < 8; ++s) accv[s] += Xs[half*8 + s][k] * wv;
    }
    #pragma unroll
    for (int s = 0; s < 8; ++s)
      giL[(half*8 + s)*384 + j] = accv[s];
  }

  // ---- recurrence weights (pair-split, w[64]/thread, no spill) ----
  int j = tid >> 1, kh = tid & 1;
  float w[64];
  const float4* wrow = (const float4*)(vWhh + (vidx*384 + j)*128 + kh*64);
  #pragma unroll
  for (int k4 = 0; k4 < 16; ++k4) {
    float4 t4 = wrow[k4];
    w[4*k4] = t4.x; w[4*k4+1] = t4.y; w[4*k4+2] = t4.z; w[4*k4+3] = t4.w;
  }
  float bj = vbhh[vidx*384 + j];
  __syncthreads();

  #pragma unroll 1
  for (int v = 0; v < 16; ++v) {
    const float4* h4 = (const float4*)(hsv + kh*64);
    float p0 = 0.f, p1 = 0.f;
    #pragma unroll
    for (int k4 = 0; k4 < 8; ++k4) {
      float4 u0 = h4[k4], u1 = h4[k4+8];
      p0 += w[4*k4   ]*u0.x + w[4*k4+1 ]*u0.y + w[4*k4+2 ]*u0.z + w[4*k4+3 ]*u0.w;
      p1 += w[4*k4+32]*u1.x + w[4*k4+33]*u1.y + w[4*k4+34]*u1.z + w[4*k4+35]*u1.w;
    }
    float part = p0 + p1;
    part += __shfl_xor(part, 1);
    if (kh == 0) gh[j] = bj + ((j < 256) ? giL[v*384 + j] : 0.f) + part;
    __syncthreads();
    if (tid < 128) {
      float r = fsig(gh[tid]);
      float z = fsig(gh[tid+128]);
      float gin = giL[v*384 + 256 + tid];
      float n = ftanh(gin + r*gh[tid+256]);
      hsv[tid] = (1.f - z)*n + z*hsv[tid];
    }
    __syncthreads();
  }
  if (tid < 128) vh[(run*16 + b)*D_ + tid] = hsv[tid];
}

// =====================================================================
// head v4 (pe fused) — verified, unchanged.
// =====================================================================
__global__ __launch_bounds__(256) void k_head(
    const float* __restrict__ vh, const float* __restrict__ Wp,
    const float* __restrict__ bp, float* __restrict__ out)
{
  const int o = blockIdx.x;
  const int tid = threadIdx.x;
  const int b = tid & 15, kc = tid >> 4;
  const int a1[7] = {0,1,2,3,4,8,9};
  const int a2[7] = {-1,5,6,7,-1,-1,-1};
  const float4* wb = (const float4*)(Wp + (size_t)o*896 + kc*56);
  float acc = 0.f;
  #pragma unroll
  for (int i = 0; i < 14; ++i) {
    int cc2 = kc*56 + i*4;
    int s = cc2 >> 7, d0 = cc2 & 127;
    float4 a = *(const float4*)(vh + (a1[s]*16 + b)*D_ + d0);
    int s2 = a2[s];
    if (s2 >= 0) {
      float4 a2v = *(const float4*)(vh + (s2*16 + b)*D_ + d0);
      a.x += a2v.x; a.y += a2v.y; a.z += a2v.z; a.w += a2v.w;
    }
    a.x = fmaxf(a.x, 0.f); a.y = fmaxf(a.y, 0.f);
    a.z = fmaxf(a.z, 0.f); a.w = fmaxf(a.w, 0.f);
    float4 ww = wb[i];
    acc += a.x*ww.x + a.y*ww.y + a.z*ww.z + a.w*ww.w;
  }
  __shared__ float red[16][17];
  red[kc][b] = acc;
  __syncthreads();
  if (tid < 16) {
    float s = 0.f;
    #pragma unroll
    for (int k = 0; k < 16; ++k) s += red[k][tid];
    out[tid*OUT_ + o] = s + bp[o];
  }
}

// =====================================================================
extern "C" void kernel_launch(void* const* d_in, const int* in_sizes, int n_in,
                              void* d_out, int out_size, void* d_ws, size_t ws_size,
                              hipStream_t stream)
{
  (void)in_sizes; (void)n_in; (void)out_size; (void)ws_size;
  const int*   cc   = (const int*)  d_in[0];
  const int*   cp   = (const int*)  d_in[1];
  const int*   cd   = (const int*)  d_in[2];
  const int*   cli  = (const int*)  d_in[3];
  const int*   clv  = (const int*)  d_in[4];
  const int*   cii  = (const int*)  d_in[5];
  const int*   civ  = (const int*)  d_in[6];
  const float* wgt  = (const float*)d_in[7];
  const float* age  = (const float*)d_in[8];
  const float* ec   = (const float*)d_in[9];
  const float* ep   = (const float*)d_in[10];
  const float* ed   = (const float*)d_in[11];
  const float* eli  = (const float*)d_in[12];
  const float* elv  = (const float*)d_in[13];
  const float* eii  = (const float*)d_in[14];
  const float* eiv  = (const float*)d_in[15];
  const float* mWih = (const float*)d_in[16];
  const float* mWhh = (const float*)d_in[17];
  const float* mbih = (const float*)d_in[18];
  const float* mbhh = (const float*)d_in[19];
  const float* vWih = (const float*)d_in[20];
  const float* vWhh = (const float*)d_in[21];
  const float* vbih = (const float*)d_in[22];
  const float* vbhh = (const float*)d_in[23];
  const float* Wself= (const float*)d_in[24];
  const float* Wmsg = (const float*)d_in[25];
  const float* fwW  = (const float*)d_in[26];
  const float* fwB  = (const float*)d_in[27];
  const float* faW  = (const float*)d_in[28];
  const float* faB  = (const float*)d_in[29];
  const float* Wp   = (const float*)d_in[30];
  const float* bp   = (const float*)d_in[31];
  float* out = (float*)d_out;
  float* ws  = (float*)d_ws;

  short* visb  = (short*)(ws + OFF_VISB);
  short* monb  = (short*)(ws + OFF_MONB);
  short* w12t  = (short*)(ws + OFF_W12T);
  short* wihb  = (short*)(ws + OFF_WIHB);
  float* wihTv = ws + OFF_WIHTV;
  float* xe    = ws + OFF_XE;
  float* last  = ws + OFF_LAST;
  float* vh    = ws + OFF_VH;

  k_prepvis<<<11584, 256, 0, stream>>>(Wself, Wmsg, mWih, vWih, wgt, age,
                                       fwW, fwB, faW, faB,
                                       cc, cp, cd, ec, ep, ed,
                                       cli, clv, cii, civ, eli, elv, eii, eiv,
                                       w12t, wihb, wihTv, xe, visb, monb);
  k_ggru<<<128, 512, 0, stream>>>(monb, visb, w12t, wihb, Wself,
                                  mWhh, mbih, mbhh, last);
  k_vgru<<<160, 768, 0, stream>>>(last, xe, wihTv, vbih, vWhh, vbhh, vh);
  k_head<<<600, 256, 0, stream>>>(vh, Wp, bp, out);
}